// Round 1
// baseline (131.926 us; speedup 1.0000x reference)
//
#include <hip/hip_runtime.h>
#include <stdint.h>

#define NBROWS 8192           // NB = B*S*T
#define KBOX   36
#define MROWS  (NBROWS * KBOX)  // 294912
#define HDIM   256

typedef __attribute__((ext_vector_type(8))) short bf16x8;  // 8 bf16 = 4 VGPR
typedef __attribute__((ext_vector_type(4))) float f32x4;

__device__ __forceinline__ unsigned short f2bf(float f) {
  unsigned int u = __float_as_uint(f);
  return (unsigned short)((u + 0x7fffu + ((u >> 16) & 1u)) >> 16);  // RNE
}

// ---------------- kernel 0: convert Wv, Wq to bf16 ----------------
__global__ void cvt_kernel(const float* __restrict__ Wv, const float* __restrict__ Wq,
                           unsigned short* __restrict__ wvb, unsigned short* __restrict__ wqb) {
  int i = blockIdx.x * 256 + threadIdx.x;  // 65536 total
  wvb[i] = f2bf(Wv[i]);
  wqb[i] = f2bf(Wq[i]);
}

// ---------------- GEMM: C = A(f32->bf16) @ W^T, fused epilogues ----------------
// MODE 0: A = q [8192x256], out g[n,h] = relu(acc + bq[h]) * Wl[h]
// MODE 1: A = v [294912x256], out logits[r] = sum_h relu(acc + bv[h]) * g[r/36, h] + bl
// Tile: BM=64 rows x BN=256 cols x BK=32. 256 threads = 4 waves, wave n-split.
template<int MODE>
__global__ __launch_bounds__(256, 4)
void gemm_kernel(const float* __restrict__ Amat,
                 const unsigned short* __restrict__ Wbf,   // 256x256 bf16 row-major (h, d)
                 const float* __restrict__ bias,           // 256
                 const float* __restrict__ wl,             // 256 (MODE 0)
                 const float* __restrict__ g,              // 8192x256 f32 (MODE 1 read)
                 float* __restrict__ outp,
                 const float* __restrict__ blp)            // scalar (MODE 1)
{
  __shared__ unsigned short Asm[64 * 32];    // 4 KB, swizzled
  __shared__ unsigned short Bsm[256 * 32];   // 16 KB, swizzled
  __shared__ float bias_sm[256];
  __shared__ float aux_sm[4 * 256];          // MODE0: Wl ; MODE1: g rows
  __shared__ float partial[64 * 4];

  const int t    = threadIdx.x;
  const int lane = t & 63;
  const int wid  = t >> 6;            // wave_n 0..3
  const int r0   = blockIdx.x * 64;

  bias_sm[t] = bias[t];
  int n_base = 0;
  if (MODE == 0) {
    aux_sm[t] = wl[t];
  } else {
    n_base = r0 / KBOX;
    #pragma unroll
    for (int i = 0; i < 4; ++i) {
      int idx = t + i * 256;
      int n = n_base + (idx >> 8);
      if (n > NBROWS - 1) n = NBROWS - 1;
      aux_sm[idx] = g[(size_t)n * 256 + (idx & 255)];
    }
  }

  f32x4 acc[4][4];
  #pragma unroll
  for (int a = 0; a < 4; ++a)
    #pragma unroll
    for (int b = 0; b < 4; ++b) acc[a][b] = (f32x4)0.f;

  const int arow = t >> 2;            // 0..63
  const int ako  = t & 3;
  const float* asrc = Amat + (size_t)(r0 + arow) * 256 + ako * 8;
  unsigned short* adst = &Asm[arow * 32 + (ako ^ ((arow >> 1) & 3)) * 8];

  for (int kk = 0; kk < 8; ++kk) {
    const int d0 = kk * 32;
    __syncthreads();   // previous iter's fragment reads done before overwrite
    // stage A: f32 -> bf16 -> LDS (swizzled 16B slots)
    {
      const float4* s4 = (const float4*)(asrc + d0);
      float4 v0 = s4[0];
      float4 v1 = s4[1];
      uint4 pk;
      pk.x = (unsigned)f2bf(v0.x) | ((unsigned)f2bf(v0.y) << 16);
      pk.y = (unsigned)f2bf(v0.z) | ((unsigned)f2bf(v0.w) << 16);
      pk.z = (unsigned)f2bf(v1.x) | ((unsigned)f2bf(v1.y) << 16);
      pk.w = (unsigned)f2bf(v1.z) | ((unsigned)f2bf(v1.w) << 16);
      *(uint4*)adst = pk;
    }
    // stage B: bf16 tile [256 rows(h) x 32 d], swizzled
    #pragma unroll
    for (int i = 0; i < 4; ++i) {
      int u = t + i * 256;
      int brow = u >> 2, bko = u & 3;
      uint4 val = *(const uint4*)&Wbf[brow * 256 + d0 + bko * 8];
      *(uint4*)&Bsm[brow * 32 + (bko ^ ((brow >> 1) & 3)) * 8] = val;
    }
    __syncthreads();
    // fragments + MFMA
    bf16x8 af[4], bfr[4];
    #pragma unroll
    for (int mf = 0; mf < 4; ++mf) {
      int row  = mf * 16 + (lane & 15);
      int phys = (lane >> 4) ^ ((row >> 1) & 3);
      af[mf] = *(const bf16x8*)&Asm[row * 32 + phys * 8];
    }
    #pragma unroll
    for (int nf = 0; nf < 4; ++nf) {
      int col  = wid * 64 + nf * 16 + (lane & 15);
      int phys = (lane >> 4) ^ ((col >> 1) & 3);
      bfr[nf] = *(const bf16x8*)&Bsm[col * 32 + phys * 8];
    }
    #pragma unroll
    for (int mf = 0; mf < 4; ++mf)
      #pragma unroll
      for (int nf = 0; nf < 4; ++nf)
        acc[mf][nf] = __builtin_amdgcn_mfma_f32_16x16x32_bf16(af[mf], bfr[nf], acc[mf][nf], 0, 0, 0);
  }

  // epilogue. C/D layout: col = lane&15, row = (lane>>4)*4 + j  [m89-verified]
  if (MODE == 0) {
    #pragma unroll
    for (int mf = 0; mf < 4; ++mf)
      #pragma unroll
      for (int nf = 0; nf < 4; ++nf) {
        int col = wid * 64 + nf * 16 + (lane & 15);
        float bb = bias_sm[col];
        float ww = aux_sm[col];
        #pragma unroll
        for (int j = 0; j < 4; ++j) {
          int row = mf * 16 + ((lane >> 4) << 2) + j;
          float x = fmaxf(acc[mf][nf][j] + bb, 0.f) * ww;
          outp[(size_t)(r0 + row) * 256 + col] = x;
        }
      }
  } else {
    float s[4][4];
    #pragma unroll
    for (int mf = 0; mf < 4; ++mf) {
      #pragma unroll
      for (int j = 0; j < 4; ++j) {
        int row  = mf * 16 + ((lane >> 4) << 2) + j;
        int nloc = (r0 + row) / KBOX - n_base;
        const float* grow = &aux_sm[nloc * 256];
        float acc_s = 0.f;
        #pragma unroll
        for (int nf = 0; nf < 4; ++nf) {
          int col = wid * 64 + nf * 16 + (lane & 15);
          float x = acc[mf][nf][j] + bias_sm[col];
          acc_s += fmaxf(x, 0.f) * grow[col];
        }
        s[mf][j] = acc_s;
      }
    }
    // reduce over the 16 lanes (lane&15) holding different cols of the same rows
    #pragma unroll
    for (int mf = 0; mf < 4; ++mf)
      #pragma unroll
      for (int j = 0; j < 4; ++j) {
        float vv = s[mf][j];
        vv += __shfl_xor(vv, 1);
        vv += __shfl_xor(vv, 2);
        vv += __shfl_xor(vv, 4);
        vv += __shfl_xor(vv, 8);
        s[mf][j] = vv;
      }
    if ((lane & 15) == 0) {
      #pragma unroll
      for (int mf = 0; mf < 4; ++mf)
        #pragma unroll
        for (int j = 0; j < 4; ++j) {
          int row = mf * 16 + ((lane >> 4) << 2) + j;
          partial[row * 4 + wid] = s[mf][j];
        }
    }
    __syncthreads();
    if (t < 64) {
      float vv = partial[t * 4 + 0] + partial[t * 4 + 1] + partial[t * 4 + 2] + partial[t * 4 + 3];
      outp[r0 + t] = vv + blp[0];
    }
  }
}

// ---------------- kernel 3: masked softmax over K=36, one wave per row ----------------
__global__ __launch_bounds__(256)
void softmax_kernel(const float* __restrict__ logits, const float* __restrict__ box_mask,
                    float* __restrict__ outp) {
  int n = blockIdx.x * 4 + (threadIdx.x >> 6);
  int k = threadIdx.x & 63;
  int b = n >> 6;  // n / (S*T) = n/64
  float l = 0.f, m = 0.f;
  if (k < KBOX) {
    m = box_mask[b * KBOX + k];
    l = logits[(size_t)n * KBOX + k];
  }
  bool act = (k < KBOX) && (m > 0.5f);
  float lm = act ? l : -3.0e38f;
  #pragma unroll
  for (int off = 32; off >= 1; off >>= 1) lm = fmaxf(lm, __shfl_xor(lm, off));
  float e = act ? expf(l - lm) : 0.f;
  float ssum = e;
  #pragma unroll
  for (int off = 32; off >= 1; off >>= 1) ssum += __shfl_xor(ssum, off);
  if (k < KBOX) outp[(size_t)n * KBOX + k] = e / ssum;
}

extern "C" void kernel_launch(void* const* d_in, const int* in_sizes, int n_in,
                              void* d_out, int out_size, void* d_ws, size_t ws_size,
                              hipStream_t stream) {
  const float* v        = (const float*)d_in[0];
  const float* q        = (const float*)d_in[1];
  const float* box_mask = (const float*)d_in[2];
  // d_in[3] = tags_attention: all ones by construction -> gather is identity (idx == n)
  const float* Wv = (const float*)d_in[4];
  const float* bv = (const float*)d_in[5];
  const float* Wq = (const float*)d_in[6];
  const float* bq = (const float*)d_in[7];
  const float* Wl = (const float*)d_in[8];
  const float* bl = (const float*)d_in[9];
  float* outp = (float*)d_out;

  char* ws = (char*)d_ws;
  unsigned short* wvb = (unsigned short*)ws;                     // 128 KB
  unsigned short* wqb = (unsigned short*)(ws + 131072);          // 128 KB
  float* g      = (float*)(ws + 262144);                         // 8 MB
  float* logits = (float*)(ws + 262144 + 8388608);               // 1.18 MB

  cvt_kernel<<<256, 256, 0, stream>>>(Wv, Wq, wvb, wqb);
  gemm_kernel<0><<<NBROWS / 64, 256, 0, stream>>>(q, wqb, bq, Wl, nullptr, g, nullptr);
  gemm_kernel<1><<<MROWS / 64, 256, 0, stream>>>(v, wvb, bv, nullptr, g, logits, bl);
  softmax_kernel<<<NBROWS / 4, 256, 0, stream>>>(logits, box_mask, outp);
}

// Round 2
// 121.574 us; speedup vs baseline: 1.0851x; 1.0851x over previous
//
#include <hip/hip_runtime.h>
#include <hip/hip_bf16.h>
#include <stdint.h>

#define NBROWS 8192           // NB = B*S*T
#define KBOX   36
#define MROWS  (NBROWS * KBOX)  // 294912

typedef __attribute__((ext_vector_type(8))) short bf16x8;  // 8 bf16 = 4 VGPR
typedef __attribute__((ext_vector_type(4))) float f32x4;

__device__ __forceinline__ unsigned short f2bf(float f) {
  unsigned int u = __float_as_uint(f);
  return (unsigned short)((u + 0x7fffu + ((u >> 16) & 1u)) >> 16);  // RNE
}

// HW bf16 convert (lowers to v_cvt_pk_bf16_f32-class ops, RNE)
__device__ __forceinline__ unsigned int pk2(float x, float y) {
  __hip_bfloat16 hx = __float2bfloat16(x);
  __hip_bfloat16 hy = __float2bfloat16(y);
  unsigned short ux, uy;
  __builtin_memcpy(&ux, &hx, 2);
  __builtin_memcpy(&uy, &hy, 2);
  return (unsigned)ux | ((unsigned)uy << 16);
}

// async global->LDS, 16B per lane; dst must be wave-uniform base (HW adds lane*16)
__device__ __forceinline__ void gll16(const void* g, void* l) {
  __builtin_amdgcn_global_load_lds((const __attribute__((address_space(1))) unsigned int*)g,
                                   (__attribute__((address_space(3))) unsigned int*)l,
                                   16, 0, 0);
}

// ---------------- kernel 0: convert Wv, Wq to bf16 ----------------
__global__ void cvt_kernel(const float* __restrict__ Wv, const float* __restrict__ Wq,
                           unsigned short* __restrict__ wvb, unsigned short* __restrict__ wqb) {
  int i = blockIdx.x * 256 + threadIdx.x;  // 65536 total
  wvb[i] = f2bf(Wv[i]);
  wqb[i] = f2bf(Wq[i]);
}

// ---------------- GEMM: C = A(f32->bf16) @ W^T, fused epilogues ----------------
// MODE 0: A = q [8192x256], out g[n,h] = relu(acc + bq[h]) * Wl[h]
// MODE 1: A = v [294912x256], out logits[r] = sum_h relu(acc + bv[h]) * g[r/36, h] + bl
// Tile: BM=64 x BN=256, BK=32, 8 K-steps. 256 threads = 4 waves (n-split).
// Double-buffered LDS; B via global_load_lds (pre-swizzled source); A reg-staged 2 ahead.
template<int MODE>
__global__ __launch_bounds__(256, 3)
void gemm_kernel(const float* __restrict__ Amat,
                 const unsigned short* __restrict__ Wbf,   // 256x256 bf16 row-major (h, d)
                 const float* __restrict__ bias,           // 256
                 const float* __restrict__ wl,             // 256 (MODE 0)
                 const float* __restrict__ g,              // 8192x256 f32 (MODE 1 read)
                 float* __restrict__ outp,
                 const float* __restrict__ blp)            // scalar (MODE 1)
{
  __shared__ unsigned short Asm[2][64 * 32];    // 2 x 4 KB, swizzled
  __shared__ unsigned short Bsm[2][256 * 32];   // 2 x 16 KB, swizzled via pre-swz source
  __shared__ float bias_sm[256];
  __shared__ float aux_sm[4 * 256];             // MODE0: Wl ; MODE1: g rows
  __shared__ float partial[64 * 4];

  const int t    = threadIdx.x;
  const int lane = t & 63;
  const int wid  = t >> 6;            // wave 0..3 (n-split)
  const int r0   = blockIdx.x * 64;

  bias_sm[t] = bias[t];
  int n_base = 0;
  if (MODE == 0) {
    aux_sm[t] = wl[t];
  } else {
    n_base = r0 / KBOX;
    #pragma unroll
    for (int i = 0; i < 4; ++i) {
      int idx = t + i * 256;
      int n = n_base + (idx >> 8);
      if (n > NBROWS - 1) n = NBROWS - 1;
      aux_sm[idx] = g[(size_t)n * 256 + (idx & 255)];
    }
  }

  // B gll geometry: wave wid, op i covers rows h = wid*64+i*16 .. +15 (16 rows x 64B = 1KB)
  // lane l -> row h = base + (l>>2), slot (l&3); pre-swizzled source chunk c = (l&3) ^ ((h>>1)&3)
  // so that reading slot p of row h yields chunk p ^ ((h>>1)&3)  [XOR swizzle, 2-way max]
  int bh[4], bco[4];
  #pragma unroll
  for (int i = 0; i < 4; ++i) {
    int h = wid * 64 + i * 16 + (lane >> 2);
    bh[i]  = h;
    bco[i] = ((lane & 3) ^ ((h >> 1) & 3)) * 8;   // element offset of chunk within row
  }

  // A staging geometry: thread t stages row arow = t>>2, chunk ako = t&3 (8 floats)
  const int arow = t >> 2;            // 0..63
  const int ako  = t & 3;
  const float* asrc = Amat + (size_t)(r0 + arow) * 256 + ako * 8;
  const int adst_off = arow * 32 + (ako ^ ((arow >> 1) & 3)) * 8;  // shorts

  f32x4 acc[4][4];
  #pragma unroll
  for (int a = 0; a < 4; ++a)
    #pragma unroll
    for (int b = 0; b < 4; ++b) acc[a][b] = (f32x4)0.f;

  float4 areg[2][2];

  // ---- prologue: B(0) via gll, A(0)+A(1) to regs, A(0) -> LDS ----
  #pragma unroll
  for (int i = 0; i < 4; ++i)
    gll16(Wbf + (size_t)bh[i] * 256 + bco[i], &Bsm[0][(wid * 64 + i * 16) * 32]);
  areg[0][0] = ((const float4*)(asrc + 0))[0];
  areg[0][1] = ((const float4*)(asrc + 0))[1];
  areg[1][0] = ((const float4*)(asrc + 32))[0];
  areg[1][1] = ((const float4*)(asrc + 32))[1];
  {
    uint4 pk;
    pk.x = pk2(areg[0][0].x, areg[0][0].y);
    pk.y = pk2(areg[0][0].z, areg[0][0].w);
    pk.z = pk2(areg[0][1].x, areg[0][1].y);
    pk.w = pk2(areg[0][1].z, areg[0][1].w);
    *(uint4*)&Asm[0][adst_off] = pk;
  }
  __syncthreads();   // drains gll B(0); Asm[0]/Bsm[0] ready

  #pragma unroll
  for (int kk = 0; kk < 8; ++kk) {
    const int cur = kk & 1;
    // stage next tile into buf[1-cur]
    if (kk < 7) {
      const int d0 = (kk + 1) * 32;
      #pragma unroll
      for (int i = 0; i < 4; ++i)
        gll16(Wbf + (size_t)bh[i] * 256 + d0 + bco[i], &Bsm[1 - cur][(wid * 64 + i * 16) * 32]);
      const float4 a0 = areg[(kk + 1) & 1][0];
      const float4 a1 = areg[(kk + 1) & 1][1];
      uint4 pk;
      pk.x = pk2(a0.x, a0.y);
      pk.y = pk2(a0.z, a0.w);
      pk.z = pk2(a1.x, a1.y);
      pk.w = pk2(a1.z, a1.w);
      *(uint4*)&Asm[1 - cur][adst_off] = pk;
    }
    // issue A(kk+2) loads (consumed next iter)
    if (kk < 6) {
      const int d0 = (kk + 2) * 32;
      areg[kk & 1][0] = ((const float4*)(asrc + d0))[0];
      areg[kk & 1][1] = ((const float4*)(asrc + d0))[1];
    }
    // compute from buf[cur]
    bf16x8 af[4], bfr[4];
    #pragma unroll
    for (int mf = 0; mf < 4; ++mf) {
      int row  = mf * 16 + (lane & 15);
      int phys = (lane >> 4) ^ ((row >> 1) & 3);
      af[mf] = *(const bf16x8*)&Asm[cur][row * 32 + phys * 8];
    }
    #pragma unroll
    for (int nf = 0; nf < 4; ++nf) {
      int col  = wid * 64 + nf * 16 + (lane & 15);
      int phys = (lane >> 4) ^ ((col >> 1) & 3);
      bfr[nf] = *(const bf16x8*)&Bsm[cur][col * 32 + phys * 8];
    }
    #pragma unroll
    for (int mf = 0; mf < 4; ++mf)
      #pragma unroll
      for (int nf = 0; nf < 4; ++nf)
        acc[mf][nf] = __builtin_amdgcn_mfma_f32_16x16x32_bf16(af[mf], bfr[nf], acc[mf][nf], 0, 0, 0);
    __syncthreads();   // writes of (kk+1) done + reads of kk done
  }

  // epilogue. C/D layout: col = lane&15, row = (lane>>4)*4 + j  [m89-verified]
  if (MODE == 0) {
    #pragma unroll
    for (int mf = 0; mf < 4; ++mf)
      #pragma unroll
      for (int nf = 0; nf < 4; ++nf) {
        int col = wid * 64 + nf * 16 + (lane & 15);
        float bb = bias_sm[col];
        float ww = aux_sm[col];
        #pragma unroll
        for (int j = 0; j < 4; ++j) {
          int row = mf * 16 + ((lane >> 4) << 2) + j;
          float x = fmaxf(acc[mf][nf][j] + bb, 0.f) * ww;
          outp[(size_t)(r0 + row) * 256 + col] = x;
        }
      }
  } else {
    float s[4][4];
    #pragma unroll
    for (int mf = 0; mf < 4; ++mf) {
      #pragma unroll
      for (int j = 0; j < 4; ++j) {
        int row  = mf * 16 + ((lane >> 4) << 2) + j;
        int nloc = (r0 + row) / KBOX - n_base;
        const float* grow = &aux_sm[nloc * 256];
        float acc_s = 0.f;
        #pragma unroll
        for (int nf = 0; nf < 4; ++nf) {
          int col = wid * 64 + nf * 16 + (lane & 15);
          float x = acc[mf][nf][j] + bias_sm[col];
          acc_s += fmaxf(x, 0.f) * grow[col];
        }
        s[mf][j] = acc_s;
      }
    }
    // reduce across the 16 lanes holding different cols of the same rows
    #pragma unroll
    for (int mf = 0; mf < 4; ++mf)
      #pragma unroll
      for (int j = 0; j < 4; ++j) {
        float vv = s[mf][j];
        vv += __shfl_xor(vv, 1);
        vv += __shfl_xor(vv, 2);
        vv += __shfl_xor(vv, 4);
        vv += __shfl_xor(vv, 8);
        s[mf][j] = vv;
      }
    if ((lane & 15) == 0) {
      #pragma unroll
      for (int mf = 0; mf < 4; ++mf)
        #pragma unroll
        for (int j = 0; j < 4; ++j) {
          int row = mf * 16 + ((lane >> 4) << 2) + j;
          partial[row * 4 + wid] = s[mf][j];
        }
    }
    __syncthreads();
    if (t < 64) {
      float vv = partial[t * 4 + 0] + partial[t * 4 + 1] + partial[t * 4 + 2] + partial[t * 4 + 3];
      outp[r0 + t] = vv + blp[0];
    }
  }
}

// ---------------- kernel 3: masked softmax over K=36, one wave per row ----------------
__global__ __launch_bounds__(256)
void softmax_kernel(const float* __restrict__ logits, const float* __restrict__ box_mask,
                    float* __restrict__ outp) {
  int n = blockIdx.x * 4 + (threadIdx.x >> 6);
  int k = threadIdx.x & 63;
  int b = n >> 6;  // n / (S*T) = n/64
  float l = 0.f, m = 0.f;
  if (k < KBOX) {
    m = box_mask[b * KBOX + k];
    l = logits[(size_t)n * KBOX + k];
  }
  bool act = (k < KBOX) && (m > 0.5f);
  float lm = act ? l : -3.0e38f;
  #pragma unroll
  for (int off = 32; off >= 1; off >>= 1) lm = fmaxf(lm, __shfl_xor(lm, off));
  float e = act ? expf(l - lm) : 0.f;
  float ssum = e;
  #pragma unroll
  for (int off = 32; off >= 1; off >>= 1) ssum += __shfl_xor(ssum, off);
  if (k < KBOX) outp[(size_t)n * KBOX + k] = e / ssum;
}

extern "C" void kernel_launch(void* const* d_in, const int* in_sizes, int n_in,
                              void* d_out, int out_size, void* d_ws, size_t ws_size,
                              hipStream_t stream) {
  const float* v        = (const float*)d_in[0];
  const float* q        = (const float*)d_in[1];
  const float* box_mask = (const float*)d_in[2];
  // d_in[3] = tags_attention: all ones by construction -> gather is identity (idx == n)
  const float* Wv = (const float*)d_in[4];
  const float* bv = (const float*)d_in[5];
  const float* Wq = (const float*)d_in[6];
  const float* bq = (const float*)d_in[7];
  const float* Wl = (const float*)d_in[8];
  const float* bl = (const float*)d_in[9];
  float* outp = (float*)d_out;

  char* ws = (char*)d_ws;
  unsigned short* wvb = (unsigned short*)ws;                     // 128 KB
  unsigned short* wqb = (unsigned short*)(ws + 131072);          // 128 KB
  float* g      = (float*)(ws + 262144);                         // 8 MB
  float* logits = (float*)(ws + 262144 + 8388608);               // 1.18 MB

  cvt_kernel<<<256, 256, 0, stream>>>(Wv, Wq, wvb, wqb);
  gemm_kernel<0><<<NBROWS / 64, 256, 0, stream>>>(q, wqb, bq, Wl, nullptr, g, nullptr);
  gemm_kernel<1><<<MROWS / 64, 256, 0, stream>>>(v, wvb, bv, nullptr, g, logits, bl);
  softmax_kernel<<<NBROWS / 4, 256, 0, stream>>>(logits, box_mask, outp);
}